// Round 12
// baseline (181.606 us; speedup 1.0000x reference)
//
#include <hip/hip_runtime.h>
#include <math.h>

#define BB 2
#define LL 2048
#define DIMV 1024
#define SSV 16
#define INNERV 1024
#define E2V 2048
#define MMV (BB*LL)      // 4096 rows
#define NCHUNK 64
#define CLEN 32          // LL / NCHUNK

typedef __attribute__((ext_vector_type(8))) short short8;   // 8 bf16 = 4 VGPRs (MFMA A/B frag)
typedef __attribute__((ext_vector_type(4))) float f32x4;    // MFMA C/D frag

static __device__ __forceinline__ float4 ld4(const float* p){
  return *reinterpret_cast<const float4*>(p);
}
// RNE fp32 -> bf16 (bit-level)
static __device__ __forceinline__ ushort f2bf(float x){
  unsigned u = __float_as_uint(x);
  unsigned r = (u + 0x7fffu + ((u >> 16) & 1u)) >> 16;
  return (ushort)r;
}
static __device__ __forceinline__ float bf2f(ushort h){
  return __uint_as_float(((unsigned)h) << 16);
}
// async global->LDS, 16B per lane; lds dest wave-uniform base + lane*16
static __device__ __forceinline__ void gld16(const void* g, void* l){
  __builtin_amdgcn_global_load_lds(
      (const __attribute__((address_space(1))) void*)g,
      (__attribute__((address_space(3))) void*)l, 16, 0, 0);
}

// ---------- fused init (weight casts + W_x transpose) + LayerNorm ----------
// blocks [0,4224): init.  [4224, 4224+MMV): LN row = blockIdx.x-4224.
__global__ __launch_bounds__(256) void ln_init(
        const float* __restrict__ x, const float* __restrict__ gamma,
        const float* __restrict__ beta, ushort* __restrict__ hh,
        const float* __restrict__ W_in, const float* __restrict__ W_dt,
        const float* __restrict__ W_out, const float* __restrict__ wx,
        ushort* __restrict__ Wih, ushort* __restrict__ Wdh,
        ushort* __restrict__ Woh, float* __restrict__ wxt){
  __shared__ float red[8];
  if (blockIdx.x < 4224){
    int idx = blockIdx.x*256 + threadIdx.x;
    if (idx < 1024*1024){
      const float* src; ushort* dst; int i;
      if (idx < 512*1024){ src = W_in;  dst = Wih; i = idx; }
      else if (idx < 768*1024){ src = W_dt;  dst = Wdh; i = idx - 512*1024; }
      else { src = W_out; dst = Woh; i = idx - 768*1024; }
      float4 v = ld4(src + (size_t)i*4);
      ushort4 H;
      H.x=f2bf(v.x); H.y=f2bf(v.y); H.z=f2bf(v.z); H.w=f2bf(v.w);
      *reinterpret_cast<ushort4*>(dst + (size_t)i*4) = H;
    } else {
      int j = idx - 1024*1024;           // [0, 32768)
      int e = j >> 10, k = j & 1023;
      wxt[k*32 + e] = wx[j];
    }
    return;
  }
  int row = blockIdx.x - 4224;
  int tid = threadIdx.x;
  const float* xr = x + (size_t)row*DIMV;
  float4 v = ld4(xr + tid*4);
  float s  = v.x+v.y+v.z+v.w;
  float s2 = v.x*v.x+v.y*v.y+v.z*v.z+v.w*v.w;
  for (int o=32;o;o>>=1){ s += __shfl_down(s,o); s2 += __shfl_down(s2,o); }
  int wid = tid>>6, lane = tid&63;
  if (lane==0){ red[wid]=s; red[4+wid]=s2; }
  __syncthreads();
  s  = red[0]+red[1]+red[2]+red[3];
  s2 = red[4]+red[5]+red[6]+red[7];
  float mu  = s*(1.f/DIMV);
  float var = s2*(1.f/DIMV) - mu*mu;
  float rstd = rsqrtf(var + 1e-5f);
  float4 g = ld4(gamma + tid*4), be = ld4(beta + tid*4);
  ushort4 H;
  H.x = f2bf((v.x-mu)*rstd*g.x + be.x);
  H.y = f2bf((v.y-mu)*rstd*g.y + be.y);
  H.z = f2bf((v.z-mu)*rstd*g.z + be.z);
  H.w = f2bf((v.w-mu)*rstd*g.w + be.w);
  *reinterpret_cast<ushort4*>(hh + (size_t)row*DIMV + tid*4) = H;
}

// ============ bf16 MFMA GEMM body: Co[M,N] = A[M,1024]*Bw[N,1024]^T ============
// m97-canonical 2-barrier-per-K-step, SINGLE LDS buffer. BK=64 (NKT=16).
// LDS rows 128B; 8x16B units/row, XOR swizzle unit^=(row&7); staged via
// inverse-swizzled global source, read with the same XOR.
// EPI 0: bf16 store. EPI 1: +aux[col], softplus, bf16 store.
// EPI 2: +aux[row*N+col], fp32 store.
#define GBK 64
#define NKT 16

template<int EPI, int BN>
static __device__ __forceinline__ void gemm_body(ushort* lds,
    const ushort* __restrict__ A, const ushort* __restrict__ Bw,
    void* __restrict__ Co_, int N, const float* __restrict__ aux,
    int bm, int bn){
  const int t  = threadIdx.x;
  const int rr  = t >> 3;                 // 0..31
  const int k16 = (t & 7) ^ (rr & 7);
  const ushort* gA = A  + (size_t)(bm + rr)*1024 + k16*8;
  const ushort* gB = Bw + (size_t)(bn + rr)*1024 + k16*8;
  const int wofs = (t >> 6) * 1024;       // wave offset inside a 4KB chunk

  const int l  = t & 63, wv = t >> 6;
  const int wm = wv & 1, wn = wv >> 1;
  const int fr = l & 15, kb = l >> 4;
  const int WN = BN/2;                    // wave col-tile (64 or 32)
  const int NF = BN/64;

  f32x4 acc[4][2*NF];
  #pragma unroll
  for (int m=0;m<4;m++){
    #pragma unroll
    for (int n=0;n<2*NF;n++) acc[m][n] = (f32x4){0.f,0.f,0.f,0.f};
  }

  char* Lb = (char*)lds;
  for (int kt = 0; kt < NKT; ++kt){
    const int ko = kt*GBK;
    gld16(gA + ko,           Lb +     0 + wofs);
    gld16(gA + ko + 32*1024, Lb +  4096 + wofs);
    gld16(gA + ko + 64*1024, Lb +  8192 + wofs);
    gld16(gA + ko + 96*1024, Lb + 12288 + wofs);
    gld16(gB + ko,           Lb + 16384 + wofs);
    gld16(gB + ko + 32*1024, Lb + 20480 + wofs);
    if (BN == 128){
      gld16(gB + ko + 64*1024, Lb + 24576 + wofs);
      gld16(gB + ko + 96*1024, Lb + 28672 + wofs);
    }
    __syncthreads();
    short8 a[4][2], b[2*NF][2];
    #pragma unroll
    for (int m=0;m<4;m++){
      int row = wm*64 + m*16 + fr;
      #pragma unroll
      for (int ks=0;ks<2;ks++)
        a[m][ks] = *(const short8*)(Lb + row*128 + (((ks*4+kb)^(fr&7))*16));
    }
    #pragma unroll
    for (int n=0;n<2*NF;n++){
      int row = wn*WN + n*16 + fr;
      #pragma unroll
      for (int ks=0;ks<2;ks++)
        b[n][ks] = *(const short8*)(Lb + 16384 + row*128 + (((ks*4+kb)^(fr&7))*16));
    }
    #pragma unroll
    for (int ks=0;ks<2;ks++){
      #pragma unroll
      for (int m=0;m<4;m++){
        #pragma unroll
        for (int n=0;n<2*NF;n++)
          acc[m][n] = __builtin_amdgcn_mfma_f32_16x16x32_bf16(a[m][ks], b[n][ks], acc[m][n], 0,0,0);
      }
    }
    __syncthreads();
  }

  // C/D layout: col = lane&15, row = (lane>>4)*4 + reg   [m89-verified]
  #pragma unroll
  for (int m=0;m<4;m++){
    int row0 = bm + wm*64 + m*16 + kb*4;
    #pragma unroll
    for (int n=0;n<2*NF;n++){
      int col = bn + wn*WN + n*16 + fr;
      #pragma unroll
      for (int j=0;j<4;j++){
        int r = row0 + j;
        float v = acc[m][n][j];
        if (EPI==0){
          ((ushort*)Co_)[(size_t)r*N + col] = f2bf(v);
        } else if (EPI==1){
          v += aux[col];
          v = (v > 20.f) ? v : log1pf(__expf(v));
          ((ushort*)Co_)[(size_t)r*N + col] = f2bf(v);
        } else {
          v += aux[(size_t)r*N + col];
          ((float*)Co_)[(size_t)r*N + col] = v;
        }
      }
    }
  }
}

template<int EPI, int BN>
__global__ __launch_bounds__(256) void gemm_bf16(
    const ushort* __restrict__ A, const ushort* __restrict__ Bw,
    void* __restrict__ Co_, int N, const float* __restrict__ aux){
  __shared__ __align__(16) ushort lds[(128+BN)*GBK];
  gemm_body<EPI,BN>(lds, A, Bw, Co_, N, aux, blockIdx.y*128, blockIdx.x*BN);
}

// ---------------- BC body: LDS-staged wxt, 4 acc chains ----------------
static __device__ __forceinline__ void bc_body(ushort* sh, float* sw,
    const ushort* __restrict__ xch, const float* __restrict__ wxt,
    float* __restrict__ bc, int blk){
  int tid = threadIdx.x;
  int row0 = blk * 8;
  const ushort4* srcH = (const ushort4*)(xch + (size_t)row0*DIMV);
  #pragma unroll
  for (int i=0;i<8;i++)
    ((ushort4*)sh)[tid + i*256] = srcH[tid + i*256];
  int r = tid >> 5, e = tid & 31;
  float a0=0.f, a1=0.f, a2=0.f, a3=0.f;
  for (int kt=0; kt<8; ++kt){
    __syncthreads();
    const float4* wsrc = (const float4*)(wxt + kt*128*32);
    #pragma unroll
    for (int i=0;i<4;i++)
      ((float4*)sw)[tid + i*256] = wsrc[tid + i*256];
    __syncthreads();
    const ushort* xr = &sh[r*1024 + kt*128];
    #pragma unroll
    for (int k=0;k<128;k+=4){
      ushort4 xv = *(const ushort4*)&xr[k];
      a0 = fmaf(bf2f(xv.x), sw[(k+0)*32+e], a0);
      a1 = fmaf(bf2f(xv.y), sw[(k+1)*32+e], a1);
      a2 = fmaf(bf2f(xv.z), sw[(k+2)*32+e], a2);
      a3 = fmaf(bf2f(xv.w), sw[(k+3)*32+e], a3);
    }
  }
  bc[(size_t)(row0 + r)*32 + e] = (a0+a1)+(a2+a3);
}

// ------- fused co-scheduled launch: gemm0b (z-half) + gemm1(dt) + bc -------
// bid<256: gemm0b tile. 256<=bid<768: gemm1 tile. bid>=768: bc block.
__global__ __launch_bounds__(256) void fused_mid(
    const ushort* __restrict__ hh, const ushort* __restrict__ Wz,
    ushort* __restrict__ zh,
    const ushort* __restrict__ xch, const ushort* __restrict__ Wdh,
    ushort* __restrict__ dtb, const float* __restrict__ b_dt,
    const float* __restrict__ wxt, float* __restrict__ bcb){
  __shared__ __align__(16) ushort lds[16384];   // 32 KB
  int bid = blockIdx.x;
  if (bid < 256){
    gemm_body<0,128>(lds, hh, Wz, zh, DIMV, nullptr, (bid>>3)*128, (bid&7)*128);
  } else if (bid < 768){
    int t2 = bid - 256;
    gemm_body<1,64>(lds, xch, Wdh, dtb, INNERV, b_dt, (t2>>4)*128, (t2&15)*64);
  } else {
    bc_body(lds, (float*)(lds + 8192), xch, wxt, bcb, bid - 768);
  }
}

// ---------------- depthwise conv(K=3,pad=1) + silu -> bf16 ----------------
// input xxh [MMV][DIMV] bf16 (xx half only)
__global__ __launch_bounds__(256) void conv_silu_kernel(const ushort* __restrict__ xxh,
        const float* __restrict__ cw, ushort* __restrict__ xch){
  int idx = blockIdx.x*256 + threadIdx.x;
  int d4  = idx & 255;
  int row = idx >> 8;
  int t = row & (LL-1);
  const ushort* p = xxh + (size_t)row*DIMV + d4*4;
  ushort4 u1 = *reinterpret_cast<const ushort4*>(p);
  ushort4 u0 = (t>0)    ? *reinterpret_cast<const ushort4*>(p - DIMV) : make_ushort4(0,0,0,0);
  ushort4 u2 = (t<LL-1) ? *reinterpret_cast<const ushort4*>(p + DIMV) : make_ushort4(0,0,0,0);
  int d = d4*4;
  float w[12];
  #pragma unroll
  for (int i=0;i<12;i++) w[i] = cw[d*3 + i];
  float4 o;
  o.x = bf2f(u0.x)*w[0] + bf2f(u1.x)*w[1]  + bf2f(u2.x)*w[2];
  o.y = bf2f(u0.y)*w[3] + bf2f(u1.y)*w[4]  + bf2f(u2.y)*w[5];
  o.z = bf2f(u0.z)*w[6] + bf2f(u1.z)*w[7]  + bf2f(u2.z)*w[8];
  o.w = bf2f(u0.w)*w[9] + bf2f(u1.w)*w[10] + bf2f(u2.w)*w[11];
  o.x = o.x / (1.f + __expf(-o.x));
  o.y = o.y / (1.f + __expf(-o.y));
  o.z = o.z / (1.f + __expf(-o.z));
  o.w = o.w / (1.f + __expf(-o.w));
  ushort4 H;
  H.x=f2bf(o.x); H.y=f2bf(o.y); H.z=f2bf(o.z); H.w=f2bf(o.w);
  *reinterpret_cast<ushort4*>(xch + (size_t)row*DIMV + d4*4) = H;
}

// ======== scan, one thread per channel d; S=16 state in registers ========
// F/P/E stored as bf16.
__global__ __launch_bounds__(256) void scan_p1(const ushort* __restrict__ dt,
        const float* __restrict__ bc, const float* __restrict__ A_log,
        ushort* __restrict__ F, ushort* __restrict__ P){
  __shared__ float sB[CLEN*32];
  int bid = blockIdx.x;                 // b*(NCHUNK*4) + c*4 + dblk
  int dblk = bid & 3;
  int c  = (bid >> 2) & (NCHUNK-1);
  int b  = bid >> 8;
  int tid = threadIdx.x;
  int d = dblk*256 + tid;
  int row0 = b*LL + c*CLEN;
  ((float4*)sB)[tid] = *((const float4*)(bc + (size_t)row0*32) + tid);
  float a[16];
  {
    const float4* ap = (const float4*)(A_log + d*16);
    #pragma unroll
    for (int q=0;q<4;q++){
      float4 v = ap[q];
      a[q*4+0]=-__expf(v.x); a[q*4+1]=-__expf(v.y);
      a[q*4+2]=-__expf(v.z); a[q*4+3]=-__expf(v.w);
    }
  }
  __syncthreads();
  float st[16];
  #pragma unroll
  for (int s=0;s<16;s++) st[s]=0.f;
  float sdt = 0.f;
  const ushort* dtp = dt + (size_t)row0*DIMV + d;
  for (int t=0;t<CLEN;t++){
    float dtv = bf2f(dtp[(size_t)t*DIMV]);
    sdt += dtv;
    float4 B0 = *(const float4*)&sB[t*32+0];
    float4 B1 = *(const float4*)&sB[t*32+4];
    float4 B2 = *(const float4*)&sB[t*32+8];
    float4 B3 = *(const float4*)&sB[t*32+12];
    float Bv[16] = {B0.x,B0.y,B0.z,B0.w,B1.x,B1.y,B1.z,B1.w,
                    B2.x,B2.y,B2.z,B2.w,B3.x,B3.y,B3.z,B3.w};
    #pragma unroll
    for (int s=0;s<16;s++){
      float dA = __expf(dtv*a[s]);
      st[s] = fmaf(st[s], dA, dtv*Bv[s]);
    }
  }
  size_t o = ((size_t)((b*NCHUNK + c)*DIMV + d))*16;
  #pragma unroll
  for (int q=0;q<4;q++){
    ushort4 fv, pv;
    fv.x=f2bf(st[q*4]);   fv.y=f2bf(st[q*4+1]);
    fv.z=f2bf(st[q*4+2]); fv.w=f2bf(st[q*4+3]);
    pv.x=f2bf(__expf(sdt*a[q*4]));   pv.y=f2bf(__expf(sdt*a[q*4+1]));
    pv.z=f2bf(__expf(sdt*a[q*4+2])); pv.w=f2bf(__expf(sdt*a[q*4+3]));
    *(ushort4*)(F + o + q*4) = fv;
    *(ushort4*)(P + o + q*4) = pv;
  }
}

__global__ __launch_bounds__(256) void scan_p2(const ushort* __restrict__ F,
        const ushort* __restrict__ P, ushort* __restrict__ E){
  int idx = blockIdx.x*256 + threadIdx.x;   // BB*DIMV*SSV = 32768
  int b  = idx >> 14;
  int ds = idx & 16383;
  float e = 0.f;
  for (int c=0;c<NCHUNK;c++){
    size_t o = ((size_t)(b*NCHUNK + c) << 14) + ds;
    E[o] = f2bf(e);
    e = fmaf(bf2f(P[o]), e, bf2f(F[o]));
  }
}

__global__ __launch_bounds__(256) void scan_p3(const ushort* __restrict__ dt,
        const float* __restrict__ bc, const float* __restrict__ A_log,
        const ushort* __restrict__ E, const ushort* __restrict__ xch,
        const ushort* __restrict__ zh, const float* __restrict__ Dp,
        ushort* __restrict__ yh){
  __shared__ float sBC[CLEN*32];
  int bid = blockIdx.x;
  int dblk = bid & 3;
  int c  = (bid >> 2) & (NCHUNK-1);
  int b  = bid >> 8;
  int tid = threadIdx.x;
  int d = dblk*256 + tid;
  int row0 = b*LL + c*CLEN;
  ((float4*)sBC)[tid] = *((const float4*)(bc + (size_t)row0*32) + tid);
  float a[16];
  {
    const float4* ap = (const float4*)(A_log + d*16);
    #pragma unroll
    for (int q=0;q<4;q++){
      float4 v = ap[q];
      a[q*4+0]=-__expf(v.x); a[q*4+1]=-__expf(v.y);
      a[q*4+2]=-__expf(v.z); a[q*4+3]=-__expf(v.w);
    }
  }
  float st[16];
  {
    size_t o = ((size_t)((b*NCHUNK + c)*DIMV + d))*16;
    #pragma unroll
    for (int q=0;q<4;q++){
      ushort4 v = *(const ushort4*)(E + o + q*4);
      st[q*4]=bf2f(v.x); st[q*4+1]=bf2f(v.y); st[q*4+2]=bf2f(v.z); st[q*4+3]=bf2f(v.w);
    }
  }
  float Dv = Dp[d];
  __syncthreads();
  const ushort* dtp = dt + (size_t)row0*DIMV + d;
  for (int t=0;t<CLEN;t++){
    float dtv = bf2f(dtp[(size_t)t*DIMV]);
    float4 B0 = *(const float4*)&sBC[t*32+0];
    float4 B1 = *(const float4*)&sBC[t*32+4];
    float4 B2 = *(const float4*)&sBC[t*32+8];
    float4 B3 = *(const float4*)&sBC[t*32+12];
    float4 C0 = *(const float4*)&sBC[t*32+16];
    float4 C1 = *(const float4*)&sBC[t*32+20];
    float4 C2 = *(const float4*)&sBC[t*32+24];
    float4 C3 = *(const float4*)&sBC[t*32+28];
    float Bv[16] = {B0.x,B0.y,B0.z,B0.w,B1.x,B1.y,B1.z,B1.w,
                    B2.x,B2.y,B2.z,B2.w,B3.x,B3.y,B3.z,B3.w};
    float Cv[16] = {C0.x,C0.y,C0.z,C0.w,C1.x,C1.y,C1.z,C1.w,
                    C2.x,C2.y,C2.z,C2.w,C3.x,C3.y,C3.z,C3.w};
    float y = 0.f;
    #pragma unroll
    for (int s=0;s<16;s++){
      float dA = __expf(dtv*a[s]);
      st[s] = fmaf(st[s], dA, dtv*Bv[s]);
      y = fmaf(st[s], Cv[s], y);
    }
    int row = row0 + t;
    size_t ofs = (size_t)row*DIMV + d;
    float xcv = bf2f(xch[ofs]);
    float zv  = bf2f(zh[ofs]);
    float sz  = zv / (1.f + __expf(-zv));
    yh[ofs] = f2bf((y + Dv*xcv)*sz);
  }
}

extern "C" void kernel_launch(void* const* d_in, const int* in_sizes, int n_in,
                              void* d_out, int out_size, void* d_ws, size_t ws_size,
                              hipStream_t stream){
  const float* x     = (const float*)d_in[0];
  const float* gamma = (const float*)d_in[1];
  const float* beta  = (const float*)d_in[2];
  const float* W_in  = (const float*)d_in[3];
  const float* cw    = (const float*)d_in[4];
  const float* W_x   = (const float*)d_in[5];
  const float* W_dt  = (const float*)d_in[6];
  const float* b_dt  = (const float*)d_in[7];
  const float* A_log = (const float*)d_in[8];
  const float* Dp    = (const float*)d_in[9];
  const float* W_out = (const float*)d_in[10];
  float* out = (float*)d_out;
  float* ws  = (float*)d_ws;
  const size_t MB = (size_t)1 << 20;   // 1M floats
  // layout (float units); bf16 buffer of N elems occupies N/2 float slots.
  ushort* xxh = (ushort*)ws;                      // 4M bf16 -> [0,2M)
  ushort* zh  = (ushort*)(ws + 2*MB);             // 4M bf16 -> [2M,4M)
  ushort* hh  = (ushort*)(ws + 4*MB);             // [4M,6M)  dead after fused_mid
  ushort* yh  = (ushort*)(ws + 4*MB);             // p3 writes (hh dead)
  ushort* xch = (ushort*)(ws + 6*MB);             // [6M,8M)
  ushort* dtb = (ushort*)(ws + 8*MB);             // [8M,10M)
  ushort* F   = (ushort*)(ws + 10*MB);            // 2M bf16 -> [10M,11M)
  ushort* P   = (ushort*)(ws + 11*MB);            // [11M,12M)
  ushort* E   = (ushort*)(ws + 12*MB);            // [12M,13M)
  ushort* Wih = (ushort*)(ws + 13*MB);            // [13M,14M)  2M ushorts
  ushort* Wdh = (ushort*)(ws + 14*MB);            // [14M,14.5M)
  ushort* Woh = (ushort*)(ws + 14*MB + 512*1024); // [14.5M,15M)
  float*  bcb = ws + 15*MB;                       // 128K floats
  float*  wxt = ws + 15*MB + 128*1024;            // 32K floats

  ln_init<<<4224 + MMV, 256, 0, stream>>>(x, gamma, beta, hh,
                                          W_in, W_dt, W_out, W_x,
                                          Wih, Wdh, Woh, wxt);
  // xx half: W_in rows [0,1024)
  gemm_bf16<0,128><<<dim3(8, MMV/128), 256, 0, stream>>>(hh, Wih, xxh, DIMV, nullptr);
  conv_silu_kernel<<<(MMV*(DIMV/4))/256, 256, 0, stream>>>(xxh, cw, xch);
  // co-scheduled: z half (W_in rows [1024,2048)) + dt gemm + bc
  fused_mid<<<1280, 256, 0, stream>>>(hh, Wih + (size_t)1024*1024, zh,
                                      xch, Wdh, dtb, b_dt, wxt, bcb);
  scan_p1<<<BB*NCHUNK*(DIMV/256), 256, 0, stream>>>(dtb, bcb, A_log, F, P);
  scan_p2<<<(BB*DIMV*SSV)/256, 256, 0, stream>>>(F, P, E);
  scan_p3<<<BB*NCHUNK*(DIMV/256), 256, 0, stream>>>(dtb, bcb, A_log, E, xch, zh, Dp, yh);
  gemm_bf16<2,64><<<dim3(DIMV/64, MMV/128), 256, 0, stream>>>(yh, Woh, out, DIMV, x);
}

// Round 14
// 154.411 us; speedup vs baseline: 1.1761x; 1.1761x over previous
//
#include <hip/hip_runtime.h>
#include <math.h>

#define BB 2
#define LL 2048
#define DIMV 1024
#define SSV 16
#define INNERV 1024
#define E2V 2048
#define MMV (BB*LL)      // 4096 rows
#define NCHUNK 64
#define CLEN 32          // LL / NCHUNK

typedef __attribute__((ext_vector_type(8))) short short8;   // 8 bf16 = 4 VGPRs (MFMA A/B frag)
typedef __attribute__((ext_vector_type(4))) float f32x4;    // MFMA C/D frag

static __device__ __forceinline__ float4 ld4(const float* p){
  return *reinterpret_cast<const float4*>(p);
}
// RNE fp32 -> bf16 (bit-level)
static __device__ __forceinline__ ushort f2bf(float x){
  unsigned u = __float_as_uint(x);
  unsigned r = (u + 0x7fffu + ((u >> 16) & 1u)) >> 16;
  return (ushort)r;
}
static __device__ __forceinline__ float bf2f(ushort h){
  return __uint_as_float(((unsigned)h) << 16);
}
// async global->LDS, 16B per lane; lds dest wave-uniform base + lane*16
static __device__ __forceinline__ void gld16(const void* g, void* l){
  __builtin_amdgcn_global_load_lds(
      (const __attribute__((address_space(1))) void*)g,
      (__attribute__((address_space(3))) void*)l, 16, 0, 0);
}

// ---------- fused init (weight casts + W_x transpose) + LayerNorm ----------
// blocks [0,4224): init.  [4224, 4224+MMV): LN row = blockIdx.x-4224.
__global__ __launch_bounds__(256) void ln_init(
        const float* __restrict__ x, const float* __restrict__ gamma,
        const float* __restrict__ beta, ushort* __restrict__ hh,
        const float* __restrict__ W_in, const float* __restrict__ W_dt,
        const float* __restrict__ W_out, const float* __restrict__ wx,
        ushort* __restrict__ Wih, ushort* __restrict__ Wdh,
        ushort* __restrict__ Woh, float* __restrict__ wxt){
  __shared__ float red[8];
  if (blockIdx.x < 4224){
    int idx = blockIdx.x*256 + threadIdx.x;
    if (idx < 1024*1024){
      const float* src; ushort* dst; int i;
      if (idx < 512*1024){ src = W_in;  dst = Wih; i = idx; }
      else if (idx < 768*1024){ src = W_dt;  dst = Wdh; i = idx - 512*1024; }
      else { src = W_out; dst = Woh; i = idx - 768*1024; }
      float4 v = ld4(src + (size_t)i*4);
      ushort4 H;
      H.x=f2bf(v.x); H.y=f2bf(v.y); H.z=f2bf(v.z); H.w=f2bf(v.w);
      *reinterpret_cast<ushort4*>(dst + (size_t)i*4) = H;
    } else {
      int j = idx - 1024*1024;           // [0, 32768)
      int e = j >> 10, k = j & 1023;
      wxt[k*32 + e] = wx[j];
    }
    return;
  }
  int row = blockIdx.x - 4224;
  int tid = threadIdx.x;
  const float* xr = x + (size_t)row*DIMV;
  float4 v = ld4(xr + tid*4);
  float s  = v.x+v.y+v.z+v.w;
  float s2 = v.x*v.x+v.y*v.y+v.z*v.z+v.w*v.w;
  for (int o=32;o;o>>=1){ s += __shfl_down(s,o); s2 += __shfl_down(s2,o); }
  int wid = tid>>6, lane = tid&63;
  if (lane==0){ red[wid]=s; red[4+wid]=s2; }
  __syncthreads();
  s  = red[0]+red[1]+red[2]+red[3];
  s2 = red[4]+red[5]+red[6]+red[7];
  float mu  = s*(1.f/DIMV);
  float var = s2*(1.f/DIMV) - mu*mu;
  float rstd = rsqrtf(var + 1e-5f);
  float4 g = ld4(gamma + tid*4), be = ld4(beta + tid*4);
  ushort4 H;
  H.x = f2bf((v.x-mu)*rstd*g.x + be.x);
  H.y = f2bf((v.y-mu)*rstd*g.y + be.y);
  H.z = f2bf((v.z-mu)*rstd*g.z + be.z);
  H.w = f2bf((v.w-mu)*rstd*g.w + be.w);
  *reinterpret_cast<ushort4*>(hh + (size_t)row*DIMV + tid*4) = H;
}

// ============ bf16 MFMA GEMM body: Co[M,N] = A[M,1024]*Bw[N,1024]^T ============
// m97-canonical 2-barrier-per-K-step, SINGLE LDS buffer. BK=64 (NKT=16).
// LDS rows 128B; 8x16B units/row, XOR swizzle unit^=(row&7); staged via
// inverse-swizzled global source, read with the same XOR.
// EPI 0: bf16 store. EPI 1: +aux[col], softplus, bf16 store.
// EPI 2: +aux[row*N+col], fp32 store.
#define GBK 64
#define NKT 16

template<int EPI, int BN>
static __device__ __forceinline__ void gemm_body(ushort* lds,
    const ushort* __restrict__ A, const ushort* __restrict__ Bw,
    void* __restrict__ Co_, int N, const float* __restrict__ aux,
    int bm, int bn){
  const int t  = threadIdx.x;
  const int rr  = t >> 3;                 // 0..31
  const int k16 = (t & 7) ^ (rr & 7);
  const ushort* gA = A  + (size_t)(bm + rr)*1024 + k16*8;
  const ushort* gB = Bw + (size_t)(bn + rr)*1024 + k16*8;
  const int wofs = (t >> 6) * 1024;       // wave offset inside a 4KB chunk

  const int l  = t & 63, wv = t >> 6;
  const int wm = wv & 1, wn = wv >> 1;
  const int fr = l & 15, kb = l >> 4;
  const int WN = BN/2;                    // wave col-tile (64 or 32)
  const int NF = BN/64;

  f32x4 acc[4][2*NF];
  #pragma unroll
  for (int m=0;m<4;m++){
    #pragma unroll
    for (int n=0;n<2*NF;n++) acc[m][n] = (f32x4){0.f,0.f,0.f,0.f};
  }

  char* Lb = (char*)lds;
  for (int kt = 0; kt < NKT; ++kt){
    const int ko = kt*GBK;
    gld16(gA + ko,           Lb +     0 + wofs);
    gld16(gA + ko + 32*1024, Lb +  4096 + wofs);
    gld16(gA + ko + 64*1024, Lb +  8192 + wofs);
    gld16(gA + ko + 96*1024, Lb + 12288 + wofs);
    gld16(gB + ko,           Lb + 16384 + wofs);
    gld16(gB + ko + 32*1024, Lb + 20480 + wofs);
    if (BN == 128){
      gld16(gB + ko + 64*1024, Lb + 24576 + wofs);
      gld16(gB + ko + 96*1024, Lb + 28672 + wofs);
    }
    __syncthreads();
    short8 a[4][2], b[2*NF][2];
    #pragma unroll
    for (int m=0;m<4;m++){
      int row = wm*64 + m*16 + fr;
      #pragma unroll
      for (int ks=0;ks<2;ks++)
        a[m][ks] = *(const short8*)(Lb + row*128 + (((ks*4+kb)^(fr&7))*16));
    }
    #pragma unroll
    for (int n=0;n<2*NF;n++){
      int row = wn*WN + n*16 + fr;
      #pragma unroll
      for (int ks=0;ks<2;ks++)
        b[n][ks] = *(const short8*)(Lb + 16384 + row*128 + (((ks*4+kb)^(fr&7))*16));
    }
    #pragma unroll
    for (int ks=0;ks<2;ks++){
      #pragma unroll
      for (int m=0;m<4;m++){
        #pragma unroll
        for (int n=0;n<2*NF;n++)
          acc[m][n] = __builtin_amdgcn_mfma_f32_16x16x32_bf16(a[m][ks], b[n][ks], acc[m][n], 0,0,0);
      }
    }
    __syncthreads();
  }

  // C/D layout: col = lane&15, row = (lane>>4)*4 + reg   [m89-verified]
  #pragma unroll
  for (int m=0;m<4;m++){
    int row0 = bm + wm*64 + m*16 + kb*4;
    #pragma unroll
    for (int n=0;n<2*NF;n++){
      int col = bn + wn*WN + n*16 + fr;
      #pragma unroll
      for (int j=0;j<4;j++){
        int r = row0 + j;
        float v = acc[m][n][j];
        if (EPI==0){
          ((ushort*)Co_)[(size_t)r*N + col] = f2bf(v);
        } else if (EPI==1){
          v += aux[col];
          v = (v > 20.f) ? v : log1pf(__expf(v));
          ((ushort*)Co_)[(size_t)r*N + col] = f2bf(v);
        } else {
          v += aux[(size_t)r*N + col];
          ((float*)Co_)[(size_t)r*N + col] = v;
        }
      }
    }
  }
}

template<int EPI, int BN>
__global__ __launch_bounds__(256) void gemm_bf16(
    const ushort* __restrict__ A, const ushort* __restrict__ Bw,
    void* __restrict__ Co_, int N, const float* __restrict__ aux){
  __shared__ __align__(16) ushort lds[(128+BN)*GBK];
  gemm_body<EPI,BN>(lds, A, Bw, Co_, N, aux, blockIdx.y*128, blockIdx.x*BN);
}

// ---------------- BC body: LDS-staged wxt (64-row chunks), 4 acc chains ----------------
// sh = 16KB (8 xc rows), sw = 8KB (64x32 wxt chunk); total 24KB.
static __device__ __forceinline__ void bc_body(ushort* sh, float* sw,
    const ushort* __restrict__ xch, const float* __restrict__ wxt,
    float* __restrict__ bc, int blk){
  int tid = threadIdx.x;
  int row0 = blk * 8;
  const ushort4* srcH = (const ushort4*)(xch + (size_t)row0*DIMV);
  #pragma unroll
  for (int i=0;i<8;i++)
    ((ushort4*)sh)[tid + i*256] = srcH[tid + i*256];
  int r = tid >> 5, e = tid & 31;
  float a0=0.f, a1=0.f, a2=0.f, a3=0.f;
  for (int kt=0; kt<16; ++kt){
    __syncthreads();                        // prior-chunk reads done (kt=0: sh staged)
    const float4* wsrc = (const float4*)(wxt + kt*64*32);   // 512 float4
    ((float4*)sw)[tid]       = wsrc[tid];
    ((float4*)sw)[tid + 256] = wsrc[tid + 256];
    __syncthreads();
    const ushort* xr = &sh[r*1024 + kt*64];
    #pragma unroll
    for (int k=0;k<64;k+=4){
      ushort4 xv = *(const ushort4*)&xr[k];
      a0 = fmaf(bf2f(xv.x), sw[(k+0)*32+e], a0);
      a1 = fmaf(bf2f(xv.y), sw[(k+1)*32+e], a1);
      a2 = fmaf(bf2f(xv.z), sw[(k+2)*32+e], a2);
      a3 = fmaf(bf2f(xv.w), sw[(k+3)*32+e], a3);
    }
  }
  bc[(size_t)(row0 + r)*32 + e] = (a0+a1)+(a2+a3);
}

// ------- fused: gemm1 (dt = softplus(xc@W_dt^T + b)) + bc (lean: 24KB LDS) -------
// blockIdx.y in [0,32): gemm tile. [32,64): bc block (y-32)*16 + x.
__global__ __launch_bounds__(256) void gemm1_bc(
    const ushort* __restrict__ xch, const ushort* __restrict__ Wdh,
    ushort* __restrict__ dtb, const float* __restrict__ b_dt,
    const float* __restrict__ wxt, float* __restrict__ bcb){
  __shared__ __align__(16) ushort lds[12288];   // 24KB
  if (blockIdx.y < 32){
    gemm_body<1,64>(lds, xch, Wdh, dtb, INNERV, b_dt, blockIdx.y*128, blockIdx.x*64);
  } else {
    bc_body(lds, (float*)(lds + 8192), xch, wxt, bcb, (blockIdx.y-32)*16 + blockIdx.x);
  }
}

// ---------------- depthwise conv(K=3,pad=1) + silu -> bf16 ----------------
// input xzh [MMV][E2V] bf16; xx = cols [0,1024)
__global__ __launch_bounds__(256) void conv_silu_kernel(const ushort* __restrict__ xz,
        const float* __restrict__ cw, ushort* __restrict__ xch){
  int idx = blockIdx.x*256 + threadIdx.x;
  int d4  = idx & 255;
  int row = idx >> 8;
  int t = row & (LL-1);
  const ushort* p = xz + (size_t)row*E2V + d4*4;
  ushort4 u1 = *reinterpret_cast<const ushort4*>(p);
  ushort4 u0 = (t>0)    ? *reinterpret_cast<const ushort4*>(p - E2V) : make_ushort4(0,0,0,0);
  ushort4 u2 = (t<LL-1) ? *reinterpret_cast<const ushort4*>(p + E2V) : make_ushort4(0,0,0,0);
  int d = d4*4;
  float w[12];
  #pragma unroll
  for (int i=0;i<12;i++) w[i] = cw[d*3 + i];
  float4 o;
  o.x = bf2f(u0.x)*w[0] + bf2f(u1.x)*w[1]  + bf2f(u2.x)*w[2];
  o.y = bf2f(u0.y)*w[3] + bf2f(u1.y)*w[4]  + bf2f(u2.y)*w[5];
  o.z = bf2f(u0.z)*w[6] + bf2f(u1.z)*w[7]  + bf2f(u2.z)*w[8];
  o.w = bf2f(u0.w)*w[9] + bf2f(u1.w)*w[10] + bf2f(u2.w)*w[11];
  o.x = o.x / (1.f + __expf(-o.x));
  o.y = o.y / (1.f + __expf(-o.y));
  o.z = o.z / (1.f + __expf(-o.z));
  o.w = o.w / (1.f + __expf(-o.w));
  ushort4 H;
  H.x=f2bf(o.x); H.y=f2bf(o.y); H.z=f2bf(o.z); H.w=f2bf(o.w);
  *reinterpret_cast<ushort4*>(xch + (size_t)row*DIMV + d4*4) = H;
}

// ======== scan, one thread per channel d; S=16 state in registers ========
// F/P/E stored as bf16 (verified: absmax unchanged, R12).
__global__ __launch_bounds__(256) void scan_p1(const ushort* __restrict__ dt,
        const float* __restrict__ bc, const float* __restrict__ A_log,
        ushort* __restrict__ F, ushort* __restrict__ P){
  __shared__ float sB[CLEN*32];
  int bid = blockIdx.x;                 // b*(NCHUNK*4) + c*4 + dblk
  int dblk = bid & 3;
  int c  = (bid >> 2) & (NCHUNK-1);
  int b  = bid >> 8;
  int tid = threadIdx.x;
  int d = dblk*256 + tid;
  int row0 = b*LL + c*CLEN;
  ((float4*)sB)[tid] = *((const float4*)(bc + (size_t)row0*32) + tid);
  float a[16];
  {
    const float4* ap = (const float4*)(A_log + d*16);
    #pragma unroll
    for (int q=0;q<4;q++){
      float4 v = ap[q];
      a[q*4+0]=-__expf(v.x); a[q*4+1]=-__expf(v.y);
      a[q*4+2]=-__expf(v.z); a[q*4+3]=-__expf(v.w);
    }
  }
  __syncthreads();
  float st[16];
  #pragma unroll
  for (int s=0;s<16;s++) st[s]=0.f;
  float sdt = 0.f;
  const ushort* dtp = dt + (size_t)row0*DIMV + d;
  for (int t=0;t<CLEN;t++){
    float dtv = bf2f(dtp[(size_t)t*DIMV]);
    sdt += dtv;
    float4 B0 = *(const float4*)&sB[t*32+0];
    float4 B1 = *(const float4*)&sB[t*32+4];
    float4 B2 = *(const float4*)&sB[t*32+8];
    float4 B3 = *(const float4*)&sB[t*32+12];
    float Bv[16] = {B0.x,B0.y,B0.z,B0.w,B1.x,B1.y,B1.z,B1.w,
                    B2.x,B2.y,B2.z,B2.w,B3.x,B3.y,B3.z,B3.w};
    #pragma unroll
    for (int s=0;s<16;s++){
      float dA = __expf(dtv*a[s]);
      st[s] = fmaf(st[s], dA, dtv*Bv[s]);
    }
  }
  size_t o = ((size_t)((b*NCHUNK + c)*DIMV + d))*16;
  #pragma unroll
  for (int q=0;q<4;q++){
    ushort4 fv, pv;
    fv.x=f2bf(st[q*4]);   fv.y=f2bf(st[q*4+1]);
    fv.z=f2bf(st[q*4+2]); fv.w=f2bf(st[q*4+3]);
    pv.x=f2bf(__expf(sdt*a[q*4]));   pv.y=f2bf(__expf(sdt*a[q*4+1]));
    pv.z=f2bf(__expf(sdt*a[q*4+2])); pv.w=f2bf(__expf(sdt*a[q*4+3]));
    *(ushort4*)(F + o + q*4) = fv;
    *(ushort4*)(P + o + q*4) = pv;
  }
}

__global__ __launch_bounds__(256) void scan_p2(const ushort* __restrict__ F,
        const ushort* __restrict__ P, ushort* __restrict__ E){
  int idx = blockIdx.x*256 + threadIdx.x;   // BB*DIMV*SSV = 32768
  int b  = idx >> 14;
  int ds = idx & 16383;
  float e = 0.f;
  for (int c=0;c<NCHUNK;c++){
    size_t o = ((size_t)(b*NCHUNK + c) << 14) + ds;
    E[o] = f2bf(e);
    e = fmaf(bf2f(P[o]), e, bf2f(F[o]));
  }
}

__global__ __launch_bounds__(256) void scan_p3(const ushort* __restrict__ dt,
        const float* __restrict__ bc, const float* __restrict__ A_log,
        const ushort* __restrict__ E, const ushort* __restrict__ xch,
        const ushort* __restrict__ xz, const float* __restrict__ Dp,
        ushort* __restrict__ yh){
  __shared__ float sBC[CLEN*32];
  int bid = blockIdx.x;
  int dblk = bid & 3;
  int c  = (bid >> 2) & (NCHUNK-1);
  int b  = bid >> 8;
  int tid = threadIdx.x;
  int d = dblk*256 + tid;
  int row0 = b*LL + c*CLEN;
  ((float4*)sBC)[tid] = *((const float4*)(bc + (size_t)row0*32) + tid);
  float a[16];
  {
    const float4* ap = (const float4*)(A_log + d*16);
    #pragma unroll
    for (int q=0;q<4;q++){
      float4 v = ap[q];
      a[q*4+0]=-__expf(v.x); a[q*4+1]=-__expf(v.y);
      a[q*4+2]=-__expf(v.z); a[q*4+3]=-__expf(v.w);
    }
  }
  float st[16];
  {
    size_t o = ((size_t)((b*NCHUNK + c)*DIMV + d))*16;
    #pragma unroll
    for (int q=0;q<4;q++){
      ushort4 v = *(const ushort4*)(E + o + q*4);
      st[q*4]=bf2f(v.x); st[q*4+1]=bf2f(v.y); st[q*4+2]=bf2f(v.z); st[q*4+3]=bf2f(v.w);
    }
  }
  float Dv = Dp[d];
  __syncthreads();
  const ushort* dtp = dt + (size_t)row0*DIMV + d;
  for (int t=0;t<CLEN;t++){
    float dtv = bf2f(dtp[(size_t)t*DIMV]);
    float4 B0 = *(const float4*)&sBC[t*32+0];
    float4 B1 = *(const float4*)&sBC[t*32+4];
    float4 B2 = *(const float4*)&sBC[t*32+8];
    float4 B3 = *(const float4*)&sBC[t*32+12];
    float4 C0 = *(const float4*)&sBC[t*32+16];
    float4 C1 = *(const float4*)&sBC[t*32+20];
    float4 C2 = *(const float4*)&sBC[t*32+24];
    float4 C3 = *(const float4*)&sBC[t*32+28];
    float Bv[16] = {B0.x,B0.y,B0.z,B0.w,B1.x,B1.y,B1.z,B1.w,
                    B2.x,B2.y,B2.z,B2.w,B3.x,B3.y,B3.z,B3.w};
    float Cv[16] = {C0.x,C0.y,C0.z,C0.w,C1.x,C1.y,C1.z,C1.w,
                    C2.x,C2.y,C2.z,C2.w,C3.x,C3.y,C3.z,C3.w};
    float y = 0.f;
    #pragma unroll
    for (int s=0;s<16;s++){
      float dA = __expf(dtv*a[s]);
      st[s] = fmaf(st[s], dA, dtv*Bv[s]);
      y = fmaf(st[s], Cv[s], y);
    }
    int row = row0 + t;
    size_t ofs = (size_t)row*DIMV + d;
    float xcv = bf2f(xch[ofs]);
    float zv  = bf2f(xz[(size_t)row*E2V + INNERV + d]);
    float sz  = zv / (1.f + __expf(-zv));
    yh[ofs] = f2bf((y + Dv*xcv)*sz);
  }
}

extern "C" void kernel_launch(void* const* d_in, const int* in_sizes, int n_in,
                              void* d_out, int out_size, void* d_ws, size_t ws_size,
                              hipStream_t stream){
  const float* x     = (const float*)d_in[0];
  const float* gamma = (const float*)d_in[1];
  const float* beta  = (const float*)d_in[2];
  const float* W_in  = (const float*)d_in[3];
  const float* cw    = (const float*)d_in[4];
  const float* W_x   = (const float*)d_in[5];
  const float* W_dt  = (const float*)d_in[6];
  const float* b_dt  = (const float*)d_in[7];
  const float* A_log = (const float*)d_in[8];
  const float* Dp    = (const float*)d_in[9];
  const float* W_out = (const float*)d_in[10];
  float* out = (float*)d_out;
  float* ws  = (float*)d_ws;
  const size_t MB = (size_t)1 << 20;   // 1M floats
  // layout (float units); bf16 buffer of N elems occupies N/2 float slots.
  ushort* xzh = (ushort*)ws;                      // 8M bf16 -> [0,4M)
  ushort* hh  = (ushort*)(ws + 4*MB);             // [4M,6M)  dead after gemm0
  ushort* yh  = (ushort*)(ws + 4*MB);             // p3 writes (hh dead)
  ushort* xch = (ushort*)(ws + 6*MB);             // [6M,8M)
  ushort* dtb = (ushort*)(ws + 8*MB);             // [8M,10M)
  ushort* F   = (ushort*)(ws + 10*MB);            // [10M,11M)
  ushort* P   = (ushort*)(ws + 11*MB);            // [11M,12M)
  ushort* E   = (ushort*)(ws + 12*MB);            // [12M,13M)
  ushort* Wih = (ushort*)(ws + 13*MB);            // [13M,14M)  2M ushorts
  ushort* Wdh = (ushort*)(ws + 14*MB);            // [14M,14.5M)
  ushort* Woh = (ushort*)(ws + 14*MB + 512*1024); // [14.5M,15M)
  float*  bcb = ws + 15*MB;                       // 128K floats
  float*  wxt = ws + 15*MB + 128*1024;            // 32K floats

  ln_init<<<4224 + MMV, 256, 0, stream>>>(x, gamma, beta, hh,
                                          W_in, W_dt, W_out, W_x,
                                          Wih, Wdh, Woh, wxt);
  gemm_bf16<0,128><<<dim3(E2V/128, MMV/128), 256, 0, stream>>>(hh, Wih, xzh, E2V, nullptr);
  conv_silu_kernel<<<(MMV*(DIMV/4))/256, 256, 0, stream>>>(xzh, cw, xch);
  gemm1_bc<<<dim3(16, 64), 256, 0, stream>>>(xch, Wdh, dtb, b_dt, wxt, bcb);
  scan_p1<<<BB*NCHUNK*(DIMV/256), 256, 0, stream>>>(dtb, bcb, A_log, F, P);
  scan_p2<<<(BB*DIMV*SSV)/256, 256, 0, stream>>>(F, P, E);
  scan_p3<<<BB*NCHUNK*(DIMV/256), 256, 0, stream>>>(dtb, bcb, A_log, E, xch, xzh, Dp, yh);
  gemm_bf16<2,64><<<dim3(DIMV/64, MMV/128), 256, 0, stream>>>(yh, Woh, out, DIMV, x);
}

// Round 16
// 154.146 us; speedup vs baseline: 1.1781x; 1.0017x over previous
//
#include <hip/hip_runtime.h>
#include <math.h>

#define BB 2
#define LL 2048
#define DIMV 1024
#define SSV 16
#define INNERV 1024
#define E2V 2048
#define MMV (BB*LL)      // 4096 rows
#define NCHUNK 64
#define CLEN 32          // LL / NCHUNK

typedef __attribute__((ext_vector_type(8))) short short8;   // 8 bf16 = 4 VGPRs (MFMA A/B frag)
typedef __attribute__((ext_vector_type(4))) float f32x4;    // MFMA C/D frag

static __device__ __forceinline__ float4 ld4(const float* p){
  return *reinterpret_cast<const float4*>(p);
}
// RNE fp32 -> bf16 (bit-level)
static __device__ __forceinline__ ushort f2bf(float x){
  unsigned u = __float_as_uint(x);
  unsigned r = (u + 0x7fffu + ((u >> 16) & 1u)) >> 16;
  return (ushort)r;
}
static __device__ __forceinline__ float bf2f(ushort h){
  return __uint_as_float(((unsigned)h) << 16);
}
// async global->LDS, 16B per lane; lds dest wave-uniform base + lane*16
static __device__ __forceinline__ void gld16(const void* g, void* l){
  __builtin_amdgcn_global_load_lds(
      (const __attribute__((address_space(1))) void*)g,
      (__attribute__((address_space(3))) void*)l, 16, 0, 0);
}

// ---------- fused init (weight casts incl. Wcat build) + LayerNorm ----------
// init thread idx sections (x4-vectorized unless noted):
//   [0,512K)      W_in  -> Wih
//   [512K,768K)   W_dt  -> Wch rows 0..1023
//   [768K,1024K)  W_out -> Woh
//   [1024K,1032K) W_x   -> Wch rows 1024..1055
//   [1032K,1056K) zero  -> Wch rows 1056..1151
// blocks [0,4224): init.  [4224, 4224+MMV): LN row = blockIdx.x-4224.
__global__ __launch_bounds__(256) void ln_init(
        const float* __restrict__ x, const float* __restrict__ gamma,
        const float* __restrict__ beta, ushort* __restrict__ hh,
        const float* __restrict__ W_in, const float* __restrict__ W_dt,
        const float* __restrict__ W_out, const float* __restrict__ wx,
        ushort* __restrict__ Wih, ushort* __restrict__ Wch,
        ushort* __restrict__ Woh){
  __shared__ float red[8];
  if (blockIdx.x < 4224){
    int idx = blockIdx.x*256 + threadIdx.x;
    if (idx < 1032*1024){
      const float* src; ushort* dst; int i;
      if (idx < 512*1024){ src = W_in;  dst = Wih; i = idx; }
      else if (idx < 768*1024){ src = W_dt;  dst = Wch; i = idx - 512*1024; }
      else if (idx < 1024*1024){ src = W_out; dst = Woh; i = idx - 768*1024; }
      else { src = wx; dst = Wch + (size_t)1024*1024; i = idx - 1024*1024; }
      float4 v = ld4(src + (size_t)i*4);
      ushort4 H;
      H.x=f2bf(v.x); H.y=f2bf(v.y); H.z=f2bf(v.z); H.w=f2bf(v.w);
      *reinterpret_cast<ushort4*>(dst + (size_t)i*4) = H;
    } else {
      int i = idx - 1032*1024;           // [0, 24576): zero rows 1056..1151
      *reinterpret_cast<ushort4*>(Wch + (size_t)1056*1024 + (size_t)i*4) =
          make_ushort4(0,0,0,0);
    }
    return;
  }
  int row = blockIdx.x - 4224;
  int tid = threadIdx.x;
  const float* xr = x + (size_t)row*DIMV;
  float4 v = ld4(xr + tid*4);
  float s  = v.x+v.y+v.z+v.w;
  float s2 = v.x*v.x+v.y*v.y+v.z*v.z+v.w*v.w;
  for (int o=32;o;o>>=1){ s += __shfl_down(s,o); s2 += __shfl_down(s2,o); }
  int wid = tid>>6, lane = tid&63;
  if (lane==0){ red[wid]=s; red[4+wid]=s2; }
  __syncthreads();
  s  = red[0]+red[1]+red[2]+red[3];
  s2 = red[4]+red[5]+red[6]+red[7];
  float mu  = s*(1.f/DIMV);
  float var = s2*(1.f/DIMV) - mu*mu;
  float rstd = rsqrtf(var + 1e-5f);
  float4 g = ld4(gamma + tid*4), be = ld4(beta + tid*4);
  ushort4 H;
  H.x = f2bf((v.x-mu)*rstd*g.x + be.x);
  H.y = f2bf((v.y-mu)*rstd*g.y + be.y);
  H.z = f2bf((v.z-mu)*rstd*g.z + be.z);
  H.w = f2bf((v.w-mu)*rstd*g.w + be.w);
  *reinterpret_cast<ushort4*>(hh + (size_t)row*DIMV + tid*4) = H;
}

// ============ bf16 MFMA GEMM body: Co[M,N] = A[M,1024]*Bw[N,1024]^T ============
// m97-canonical 2-barrier-per-K-step, SINGLE LDS buffer. BK=64 (NKT=16).
// LDS rows 128B; 8x16B units/row, XOR swizzle unit^=(row&7); staged via
// inverse-swizzled global source, read with the same XOR.
// EPI 0: bf16 store. EPI 2: +aux[row*N+col], fp32 store.
// EPI 3: split epilogue — col<1024: softplus(+aux[col]) bf16 -> Co_ (stride 1024);
//        1024<=col<1056: fp32 -> aux2[row*32 + col-1024]; col>=1056: discard.
#define GBK 64
#define NKT 16

template<int EPI, int BN>
static __device__ __forceinline__ void gemm_body(ushort* lds,
    const ushort* __restrict__ A, const ushort* __restrict__ Bw,
    void* __restrict__ Co_, int N, const float* __restrict__ aux,
    float* __restrict__ aux2, int bm, int bn){
  const int t  = threadIdx.x;
  const int rr  = t >> 3;                 // 0..31
  const int k16 = (t & 7) ^ (rr & 7);
  const ushort* gA = A  + (size_t)(bm + rr)*1024 + k16*8;
  const ushort* gB = Bw + (size_t)(bn + rr)*1024 + k16*8;
  const int wofs = (t >> 6) * 1024;       // wave offset inside a 4KB chunk

  const int l  = t & 63, wv = t >> 6;
  const int wm = wv & 1, wn = wv >> 1;
  const int fr = l & 15, kb = l >> 4;
  const int WN = BN/2;                    // wave col-tile (64 or 32)
  const int NF = BN/64;

  f32x4 acc[4][2*NF];
  #pragma unroll
  for (int m=0;m<4;m++){
    #pragma unroll
    for (int n=0;n<2*NF;n++) acc[m][n] = (f32x4){0.f,0.f,0.f,0.f};
  }

  char* Lb = (char*)lds;
  for (int kt = 0; kt < NKT; ++kt){
    const int ko = kt*GBK;
    gld16(gA + ko,           Lb +     0 + wofs);
    gld16(gA + ko + 32*1024, Lb +  4096 + wofs);
    gld16(gA + ko + 64*1024, Lb +  8192 + wofs);
    gld16(gA + ko + 96*1024, Lb + 12288 + wofs);
    gld16(gB + ko,           Lb + 16384 + wofs);
    gld16(gB + ko + 32*1024, Lb + 20480 + wofs);
    if (BN == 128){
      gld16(gB + ko + 64*1024, Lb + 24576 + wofs);
      gld16(gB + ko + 96*1024, Lb + 28672 + wofs);
    }
    __syncthreads();
    short8 a[4][2], b[2*NF][2];
    #pragma unroll
    for (int m=0;m<4;m++){
      int row = wm*64 + m*16 + fr;
      #pragma unroll
      for (int ks=0;ks<2;ks++)
        a[m][ks] = *(const short8*)(Lb + row*128 + (((ks*4+kb)^(fr&7))*16));
    }
    #pragma unroll
    for (int n=0;n<2*NF;n++){
      int row = wn*WN + n*16 + fr;
      #pragma unroll
      for (int ks=0;ks<2;ks++)
        b[n][ks] = *(const short8*)(Lb + 16384 + row*128 + (((ks*4+kb)^(fr&7))*16));
    }
    #pragma unroll
    for (int ks=0;ks<2;ks++){
      #pragma unroll
      for (int m=0;m<4;m++){
        #pragma unroll
        for (int n=0;n<2*NF;n++)
          acc[m][n] = __builtin_amdgcn_mfma_f32_16x16x32_bf16(a[m][ks], b[n][ks], acc[m][n], 0,0,0);
      }
    }
    __syncthreads();
  }

  // C/D layout: col = lane&15, row = (lane>>4)*4 + reg   [m89-verified]
  #pragma unroll
  for (int m=0;m<4;m++){
    int row0 = bm + wm*64 + m*16 + kb*4;
    #pragma unroll
    for (int n=0;n<2*NF;n++){
      int col = bn + wn*WN + n*16 + fr;
      #pragma unroll
      for (int j=0;j<4;j++){
        int r = row0 + j;
        float v = acc[m][n][j];
        if (EPI==0){
          ((ushort*)Co_)[(size_t)r*N + col] = f2bf(v);
        } else if (EPI==2){
          v += aux[(size_t)r*N + col];
          ((float*)Co_)[(size_t)r*N + col] = v;
        } else {  // EPI==3
          if (col < 1024){
            v += aux[col];
            v = (v > 20.f) ? v : log1pf(__expf(v));
            ((ushort*)Co_)[(size_t)r*1024 + col] = f2bf(v);
          } else if (col < 1056){
            aux2[(size_t)r*32 + (col - 1024)] = v;
          }
        }
      }
    }
  }
}

template<int EPI, int BN>
__global__ __launch_bounds__(256) void gemm_bf16(
    const ushort* __restrict__ A, const ushort* __restrict__ Bw,
    void* __restrict__ Co_, int N, const float* __restrict__ aux){
  __shared__ __align__(16) ushort lds[(128+BN)*GBK];
  gemm_body<EPI,BN>(lds, A, Bw, Co_, N, aux, nullptr, blockIdx.y*128, blockIdx.x*BN);
}

// ------- dt||BC combined GEMM: xc @ Wcat^T, Wcat = [W_dt;W_x;pad] (1152 rows) -------
__global__ __launch_bounds__(256) void gemm_dtbc(
    const ushort* __restrict__ xch, const ushort* __restrict__ Wch,
    ushort* __restrict__ dtb, const float* __restrict__ b_dt,
    float* __restrict__ bcb){
  __shared__ __align__(16) ushort lds[(128+64)*GBK];
  gemm_body<3,64>(lds, xch, Wch, dtb, 1024, b_dt, bcb, blockIdx.y*128, blockIdx.x*64);
}

// ---------------- depthwise conv(K=3,pad=1) + silu -> bf16 ----------------
// input xzh [MMV][E2V] bf16; xx = cols [0,1024)
__global__ __launch_bounds__(256) void conv_silu_kernel(const ushort* __restrict__ xz,
        const float* __restrict__ cw, ushort* __restrict__ xch){
  int idx = blockIdx.x*256 + threadIdx.x;
  int d4  = idx & 255;
  int row = idx >> 8;
  int t = row & (LL-1);
  const ushort* p = xz + (size_t)row*E2V + d4*4;
  ushort4 u1 = *reinterpret_cast<const ushort4*>(p);
  ushort4 u0 = (t>0)    ? *reinterpret_cast<const ushort4*>(p - E2V) : make_ushort4(0,0,0,0);
  ushort4 u2 = (t<LL-1) ? *reinterpret_cast<const ushort4*>(p + E2V) : make_ushort4(0,0,0,0);
  int d = d4*4;
  float w[12];
  #pragma unroll
  for (int i=0;i<12;i++) w[i] = cw[d*3 + i];
  float4 o;
  o.x = bf2f(u0.x)*w[0] + bf2f(u1.x)*w[1]  + bf2f(u2.x)*w[2];
  o.y = bf2f(u0.y)*w[3] + bf2f(u1.y)*w[4]  + bf2f(u2.y)*w[5];
  o.z = bf2f(u0.z)*w[6] + bf2f(u1.z)*w[7]  + bf2f(u2.z)*w[8];
  o.w = bf2f(u0.w)*w[9] + bf2f(u1.w)*w[10] + bf2f(u2.w)*w[11];
  o.x = o.x / (1.f + __expf(-o.x));
  o.y = o.y / (1.f + __expf(-o.y));
  o.z = o.z / (1.f + __expf(-o.z));
  o.w = o.w / (1.f + __expf(-o.w));
  ushort4 H;
  H.x=f2bf(o.x); H.y=f2bf(o.y); H.z=f2bf(o.z); H.w=f2bf(o.w);
  *reinterpret_cast<ushort4*>(xch + (size_t)row*DIMV + d4*4) = H;
}

// ======== scan, one thread per channel d; S=16 state in registers ========
// F/P/E stored as bf16 (verified: absmax unchanged, R12).
__global__ __launch_bounds__(256) void scan_p1(const ushort* __restrict__ dt,
        const float* __restrict__ bc, const float* __restrict__ A_log,
        ushort* __restrict__ F, ushort* __restrict__ P){
  __shared__ float sB[CLEN*32];
  int bid = blockIdx.x;                 // b*(NCHUNK*4) + c*4 + dblk
  int dblk = bid & 3;
  int c  = (bid >> 2) & (NCHUNK-1);
  int b  = bid >> 8;
  int tid = threadIdx.x;
  int d = dblk*256 + tid;
  int row0 = b*LL + c*CLEN;
  ((float4*)sB)[tid] = *((const float4*)(bc + (size_t)row0*32) + tid);
  float a[16];
  {
    const float4* ap = (const float4*)(A_log + d*16);
    #pragma unroll
    for (int q=0;q<4;q++){
      float4 v = ap[q];
      a[q*4+0]=-__expf(v.x); a[q*4+1]=-__expf(v.y);
      a[q*4+2]=-__expf(v.z); a[q*4+3]=-__expf(v.w);
    }
  }
  __syncthreads();
  float st[16];
  #pragma unroll
  for (int s=0;s<16;s++) st[s]=0.f;
  float sdt = 0.f;
  const ushort* dtp = dt + (size_t)row0*DIMV + d;
  for (int t=0;t<CLEN;t++){
    float dtv = bf2f(dtp[(size_t)t*DIMV]);
    sdt += dtv;
    float4 B0 = *(const float4*)&sB[t*32+0];
    float4 B1 = *(const float4*)&sB[t*32+4];
    float4 B2 = *(const float4*)&sB[t*32+8];
    float4 B3 = *(const float4*)&sB[t*32+12];
    float Bv[16] = {B0.x,B0.y,B0.z,B0.w,B1.x,B1.y,B1.z,B1.w,
                    B2.x,B2.y,B2.z,B2.w,B3.x,B3.y,B3.z,B3.w};
    #pragma unroll
    for (int s=0;s<16;s++){
      float dA = __expf(dtv*a[s]);
      st[s] = fmaf(st[s], dA, dtv*Bv[s]);
    }
  }
  size_t o = ((size_t)((b*NCHUNK + c)*DIMV + d))*16;
  #pragma unroll
  for (int q=0;q<4;q++){
    ushort4 fv, pv;
    fv.x=f2bf(st[q*4]);   fv.y=f2bf(st[q*4+1]);
    fv.z=f2bf(st[q*4+2]); fv.w=f2bf(st[q*4+3]);
    pv.x=f2bf(__expf(sdt*a[q*4]));   pv.y=f2bf(__expf(sdt*a[q*4+1]));
    pv.z=f2bf(__expf(sdt*a[q*4+2])); pv.w=f2bf(__expf(sdt*a[q*4+3]));
    *(ushort4*)(F + o + q*4) = fv;
    *(ushort4*)(P + o + q*4) = pv;
  }
}

__global__ __launch_bounds__(256) void scan_p2(const ushort* __restrict__ F,
        const ushort* __restrict__ P, ushort* __restrict__ E){
  int idx = blockIdx.x*256 + threadIdx.x;   // BB*DIMV*SSV = 32768
  int b  = idx >> 14;
  int ds = idx & 16383;
  float e = 0.f;
  for (int c=0;c<NCHUNK;c++){
    size_t o = ((size_t)(b*NCHUNK + c) << 14) + ds;
    E[o] = f2bf(e);
    e = fmaf(bf2f(P[o]), e, bf2f(F[o]));
  }
}

__global__ __launch_bounds__(256) void scan_p3(const ushort* __restrict__ dt,
        const float* __restrict__ bc, const float* __restrict__ A_log,
        const ushort* __restrict__ E, const ushort* __restrict__ xch,
        const ushort* __restrict__ xz, const float* __restrict__ Dp,
        ushort* __restrict__ yh){
  __shared__ float sBC[CLEN*32];
  int bid = blockIdx.x;
  int dblk = bid & 3;
  int c  = (bid >> 2) & (NCHUNK-1);
  int b  = bid >> 8;
  int tid = threadIdx.x;
  int d = dblk*256 + tid;
  int row0 = b*LL + c*CLEN;
  ((float4*)sBC)[tid] = *((const float4*)(bc + (size_t)row0*32) + tid);
  float a[16];
  {
    const float4* ap = (const float4*)(A_log + d*16);
    #pragma unroll
    for (int q=0;q<4;q++){
      float4 v = ap[q];
      a[q*4+0]=-__expf(v.x); a[q*4+1]=-__expf(v.y);
      a[q*4+2]=-__expf(v.z); a[q*4+3]=-__expf(v.w);
    }
  }
  float st[16];
  {
    size_t o = ((size_t)((b*NCHUNK + c)*DIMV + d))*16;
    #pragma unroll
    for (int q=0;q<4;q++){
      ushort4 v = *(const ushort4*)(E + o + q*4);
      st[q*4]=bf2f(v.x); st[q*4+1]=bf2f(v.y); st[q*4+2]=bf2f(v.z); st[q*4+3]=bf2f(v.w);
    }
  }
  float Dv = Dp[d];
  __syncthreads();
  const ushort* dtp = dt + (size_t)row0*DIMV + d;
  for (int t=0;t<CLEN;t++){
    float dtv = bf2f(dtp[(size_t)t*DIMV]);
    float4 B0 = *(const float4*)&sBC[t*32+0];
    float4 B1 = *(const float4*)&sBC[t*32+4];
    float4 B2 = *(const float4*)&sBC[t*32+8];
    float4 B3 = *(const float4*)&sBC[t*32+12];
    float4 C0 = *(const float4*)&sBC[t*32+16];
    float4 C1 = *(const float4*)&sBC[t*32+20];
    float4 C2 = *(const float4*)&sBC[t*32+24];
    float4 C3 = *(const float4*)&sBC[t*32+28];
    float Bv[16] = {B0.x,B0.y,B0.z,B0.w,B1.x,B1.y,B1.z,B1.w,
                    B2.x,B2.y,B2.z,B2.w,B3.x,B3.y,B3.z,B3.w};
    float Cv[16] = {C0.x,C0.y,C0.z,C0.w,C1.x,C1.y,C1.z,C1.w,
                    C2.x,C2.y,C2.z,C2.w,C3.x,C3.y,C3.z,C3.w};
    float y = 0.f;
    #pragma unroll
    for (int s=0;s<16;s++){
      float dA = __expf(dtv*a[s]);
      st[s] = fmaf(st[s], dA, dtv*Bv[s]);
      y = fmaf(st[s], Cv[s], y);
    }
    int row = row0 + t;
    size_t ofs = (size_t)row*DIMV + d;
    float xcv = bf2f(xch[ofs]);
    float zv  = bf2f(xz[(size_t)row*E2V + INNERV + d]);
    float sz  = zv / (1.f + __expf(-zv));
    yh[ofs] = f2bf((y + Dv*xcv)*sz);
  }
}

extern "C" void kernel_launch(void* const* d_in, const int* in_sizes, int n_in,
                              void* d_out, int out_size, void* d_ws, size_t ws_size,
                              hipStream_t stream){
  const float* x     = (const float*)d_in[0];
  const float* gamma = (const float*)d_in[1];
  const float* beta  = (const float*)d_in[2];
  const float* W_in  = (const float*)d_in[3];
  const float* cw    = (const float*)d_in[4];
  const float* W_x   = (const float*)d_in[5];
  const float* W_dt  = (const float*)d_in[6];
  const float* b_dt  = (const float*)d_in[7];
  const float* A_log = (const float*)d_in[8];
  const float* Dp    = (const float*)d_in[9];
  const float* W_out = (const float*)d_in[10];
  float* out = (float*)d_out;
  float* ws  = (float*)d_ws;
  const size_t MB = (size_t)1 << 20;   // 1M floats
  // layout (float units); bf16 buffer of N elems occupies N/2 float slots.
  ushort* xzh = (ushort*)ws;                      // 8M bf16 -> [0,4M)
  ushort* hh  = (ushort*)(ws + 4*MB);             // [4M,6M)  dead after gemm0
  ushort* yh  = (ushort*)(ws + 4*MB);             // p3 writes (hh dead)
  ushort* xch = (ushort*)(ws + 6*MB);             // [6M,8M)
  ushort* dtb = (ushort*)(ws + 8*MB);             // [8M,10M)
  ushort* F   = (ushort*)(ws + 10*MB);            // [10M,11M)
  ushort* P   = (ushort*)(ws + 11*MB);            // [11M,12M)
  ushort* E   = (ushort*)(ws + 12*MB);            // [12M,13M)
  ushort* Wih = (ushort*)(ws + 13*MB);            // [13M,14M)  2M ushorts
  ushort* Wch = (ushort*)(ws + 14*MB);            // [14M,14.6M) 1152x1024 ushorts
  ushort* Woh = (ushort*)(ws + 14*MB + 640*1024); // [14.625M,15.125M)
  float*  bcb = ws + 15*MB + 256*1024;            // [15.25M, +128K floats)

  ln_init<<<4224 + MMV, 256, 0, stream>>>(x, gamma, beta, hh,
                                          W_in, W_dt, W_out, W_x,
                                          Wih, Wch, Woh);
  gemm_bf16<0,128><<<dim3(E2V/128, MMV/128), 256, 0, stream>>>(hh, Wih, xzh, E2V, nullptr);
  conv_silu_kernel<<<(MMV*(DIMV/4))/256, 256, 0, stream>>>(xzh, cw, xch);
  gemm_dtbc<<<dim3(17, MMV/128), 256, 0, stream>>>(xch, Wch, dtb, b_dt, bcb);
  scan_p1<<<BB*NCHUNK*(DIMV/256), 256, 0, stream>>>(dtb, bcb, A_log, F, P);
  scan_p2<<<(BB*DIMV*SSV)/256, 256, 0, stream>>>(F, P, E);
  scan_p3<<<BB*NCHUNK*(DIMV/256), 256, 0, stream>>>(dtb, bcb, A_log, E, xch, xzh, Dp, yh);
  gemm_bf16<2,64><<<dim3(DIMV/64, MMV/128), 256, 0, stream>>>(yh, Woh, out, DIMV, x);
}

// Round 18
// 152.359 us; speedup vs baseline: 1.1920x; 1.0117x over previous
//
#include <hip/hip_runtime.h>
#include <math.h>

#define BB 2
#define LL 2048
#define DIMV 1024
#define SSV 16
#define INNERV 1024
#define E2V 2048
#define MMV (BB*LL)      // 4096 rows
#define NCHUNK 64
#define CLEN 32          // LL / NCHUNK

typedef __attribute__((ext_vector_type(8))) short short8;   // 8 bf16 = 4 VGPRs (MFMA A/B frag)
typedef __attribute__((ext_vector_type(4))) float f32x4;    // MFMA C/D frag

static __device__ __forceinline__ float4 ld4(const float* p){
  return *reinterpret_cast<const float4*>(p);
}
// RNE fp32 -> bf16 (bit-level)
static __device__ __forceinline__ ushort f2bf(float x){
  unsigned u = __float_as_uint(x);
  unsigned r = (u + 0x7fffu + ((u >> 16) & 1u)) >> 16;
  return (ushort)r;
}
static __device__ __forceinline__ float bf2f(ushort h){
  return __uint_as_float(((unsigned)h) << 16);
}
// async global->LDS, 16B per lane; lds dest wave-uniform base + lane*16
static __device__ __forceinline__ void gld16(const void* g, void* l){
  __builtin_amdgcn_global_load_lds(
      (const __attribute__((address_space(1))) void*)g,
      (__attribute__((address_space(3))) void*)l, 16, 0, 0);
}

// ---------- fused init (weight casts incl. Wcat build) + LayerNorm ----------
// init thread idx sections (x4-vectorized unless noted):
//   [0,512K)      W_in  -> Wih
//   [512K,768K)   W_dt  -> Wch rows 0..1023
//   [768K,1024K)  W_out -> Woh
//   [1024K,1032K) W_x   -> Wch rows 1024..1055
//   [1032K,1056K) zero  -> Wch rows 1056..1151
// blocks [0,4224): init.  [4224, 4224+MMV): LN row = blockIdx.x-4224.
__global__ __launch_bounds__(256) void ln_init(
        const float* __restrict__ x, const float* __restrict__ gamma,
        const float* __restrict__ beta, ushort* __restrict__ hh,
        const float* __restrict__ W_in, const float* __restrict__ W_dt,
        const float* __restrict__ W_out, const float* __restrict__ wx,
        ushort* __restrict__ Wih, ushort* __restrict__ Wch,
        ushort* __restrict__ Woh){
  __shared__ float red[8];
  if (blockIdx.x < 4224){
    int idx = blockIdx.x*256 + threadIdx.x;
    if (idx < 1032*1024){
      const float* src; ushort* dst; int i;
      if (idx < 512*1024){ src = W_in;  dst = Wih; i = idx; }
      else if (idx < 768*1024){ src = W_dt;  dst = Wch; i = idx - 512*1024; }
      else if (idx < 1024*1024){ src = W_out; dst = Woh; i = idx - 768*1024; }
      else { src = wx; dst = Wch + (size_t)1024*1024; i = idx - 1024*1024; }
      float4 v = ld4(src + (size_t)i*4);
      ushort4 H;
      H.x=f2bf(v.x); H.y=f2bf(v.y); H.z=f2bf(v.z); H.w=f2bf(v.w);
      *reinterpret_cast<ushort4*>(dst + (size_t)i*4) = H;
    } else {
      int i = idx - 1032*1024;           // [0, 24576): zero rows 1056..1151
      *reinterpret_cast<ushort4*>(Wch + (size_t)1056*1024 + (size_t)i*4) =
          make_ushort4(0,0,0,0);
    }
    return;
  }
  int row = blockIdx.x - 4224;
  int tid = threadIdx.x;
  const float* xr = x + (size_t)row*DIMV;
  float4 v = ld4(xr + tid*4);
  float s  = v.x+v.y+v.z+v.w;
  float s2 = v.x*v.x+v.y*v.y+v.z*v.z+v.w*v.w;
  for (int o=32;o;o>>=1){ s += __shfl_down(s,o); s2 += __shfl_down(s2,o); }
  int wid = tid>>6, lane = tid&63;
  if (lane==0){ red[wid]=s; red[4+wid]=s2; }
  __syncthreads();
  s  = red[0]+red[1]+red[2]+red[3];
  s2 = red[4]+red[5]+red[6]+red[7];
  float mu  = s*(1.f/DIMV);
  float var = s2*(1.f/DIMV) - mu*mu;
  float rstd = rsqrtf(var + 1e-5f);
  float4 g = ld4(gamma + tid*4), be = ld4(beta + tid*4);
  ushort4 H;
  H.x = f2bf((v.x-mu)*rstd*g.x + be.x);
  H.y = f2bf((v.y-mu)*rstd*g.y + be.y);
  H.z = f2bf((v.z-mu)*rstd*g.z + be.z);
  H.w = f2bf((v.w-mu)*rstd*g.w + be.w);
  *reinterpret_cast<ushort4*>(hh + (size_t)row*DIMV + tid*4) = H;
}

// ============ bf16 MFMA GEMM body: Co[M,N] = A[M,1024]*Bw[N,1024]^T ============
// m97-canonical 2-barrier-per-K-step, SINGLE LDS buffer. BK=128 (NKT=8) —
// halves barrier-drain count vs BK=64 (GEMMs here are grid-starved at ~2
// blocks/CU, latency-bound on the vmcnt(0) drain; LDS is not the limiter).
// LDS rows 256B (128 bf16) = 16x16B units; XOR swizzle unit^=(row&15);
// staged via inverse-swizzled global source (k16=(t&15)^(t>>4)), read with
// the same XOR (((ks*4+kb)^fr)*16).
// EPI 0: bf16 store. EPI 2: +aux[row*N+col], fp32 store.
// EPI 3: split epilogue — col<1024: softplus(+aux[col]) bf16 -> Co_ (stride 1024);
//        1024<=col<1056: fp32 -> aux2[row*32 + col-1024]; col>=1056: discard.
#define GBK 128
#define NKT 8

template<int EPI, int BN>
static __device__ __forceinline__ void gemm_body(ushort* lds,
    const ushort* __restrict__ A, const ushort* __restrict__ Bw,
    void* __restrict__ Co_, int N, const float* __restrict__ aux,
    float* __restrict__ aux2, int bm, int bn){
  const int t  = threadIdx.x;
  const int rr  = t >> 4;                 // 0..15: row within a 16-row chunk
  const int k16 = (t & 15) ^ rr;          // logical 16B unit fetched
  const ushort* gA = A  + (size_t)(bm + rr)*1024 + k16*8;
  const ushort* gB = Bw + (size_t)(bn + rr)*1024 + k16*8;
  const int wofs = (t >> 6) * 1024;       // wave offset inside a 4KB chunk

  const int l  = t & 63, wv = t >> 6;
  const int wm = wv & 1, wn = wv >> 1;
  const int fr = l & 15, kb = l >> 4;
  const int WN = BN/2;                    // wave col-tile (64 or 32)
  const int NF = BN/64;

  f32x4 acc[4][2*NF];
  #pragma unroll
  for (int m=0;m<4;m++){
    #pragma unroll
    for (int n=0;n<2*NF;n++) acc[m][n] = (f32x4){0.f,0.f,0.f,0.f};
  }

  char* Lb = (char*)lds;
  for (int kt = 0; kt < NKT; ++kt){
    const int ko = kt*GBK;
    #pragma unroll
    for (int c=0;c<8;c++)                 // A: 128 rows = 8 chunks of 16
      gld16(gA + ko + c*16384, Lb + c*4096 + wofs);
    #pragma unroll
    for (int c=0;c<BN/16;c++)             // B: BN rows
      gld16(gB + ko + c*16384, Lb + 32768 + c*4096 + wofs);
    __syncthreads();
    #pragma unroll
    for (int ks=0;ks<4;ks++){
      short8 a[4], b[2*NF];
      #pragma unroll
      for (int m=0;m<4;m++){
        int row = wm*64 + m*16 + fr;
        a[m] = *(const short8*)(Lb + row*256 + (((ks*4+kb)^fr)*16));
      }
      #pragma unroll
      for (int n=0;n<2*NF;n++){
        int row = wn*WN + n*16 + fr;
        b[n] = *(const short8*)(Lb + 32768 + row*256 + (((ks*4+kb)^fr)*16));
      }
      #pragma unroll
      for (int m=0;m<4;m++){
        #pragma unroll
        for (int n=0;n<2*NF;n++)
          acc[m][n] = __builtin_amdgcn_mfma_f32_16x16x32_bf16(a[m], b[n], acc[m][n], 0,0,0);
      }
    }
    __syncthreads();
  }

  // C/D layout: col = lane&15, row = (lane>>4)*4 + reg   [m89-verified]
  #pragma unroll
  for (int m=0;m<4;m++){
    int row0 = bm + wm*64 + m*16 + kb*4;
    #pragma unroll
    for (int n=0;n<2*NF;n++){
      int col = bn + wn*WN + n*16 + fr;
      #pragma unroll
      for (int j=0;j<4;j++){
        int r = row0 + j;
        float v = acc[m][n][j];
        if (EPI==0){
          ((ushort*)Co_)[(size_t)r*N + col] = f2bf(v);
        } else if (EPI==2){
          v += aux[(size_t)r*N + col];
          ((float*)Co_)[(size_t)r*N + col] = v;
        } else {  // EPI==3
          if (col < 1024){
            v += aux[col];
            v = (v > 20.f) ? v : log1pf(__expf(v));
            ((ushort*)Co_)[(size_t)r*1024 + col] = f2bf(v);
          } else if (col < 1056){
            aux2[(size_t)r*32 + (col - 1024)] = v;
          }
        }
      }
    }
  }
}

template<int EPI, int BN>
__global__ __launch_bounds__(256) void gemm_bf16(
    const ushort* __restrict__ A, const ushort* __restrict__ Bw,
    void* __restrict__ Co_, int N, const float* __restrict__ aux){
  __shared__ __align__(16) ushort lds[(128+BN)*GBK];
  gemm_body<EPI,BN>(lds, A, Bw, Co_, N, aux, nullptr, blockIdx.y*128, blockIdx.x*BN);
}

// ------- dt||BC combined GEMM: xc @ Wcat^T, Wcat = [W_dt;W_x;pad] (1152 rows) -------
__global__ __launch_bounds__(256) void gemm_dtbc(
    const ushort* __restrict__ xch, const ushort* __restrict__ Wch,
    ushort* __restrict__ dtb, const float* __restrict__ b_dt,
    float* __restrict__ bcb){
  __shared__ __align__(16) ushort lds[(128+64)*GBK];
  gemm_body<3,64>(lds, xch, Wch, dtb, 1024, b_dt, bcb, blockIdx.y*128, blockIdx.x*64);
}

// ---------------- depthwise conv(K=3,pad=1) + silu -> bf16 ----------------
// input xzh [MMV][E2V] bf16; xx = cols [0,1024)
__global__ __launch_bounds__(256) void conv_silu_kernel(const ushort* __restrict__ xz,
        const float* __restrict__ cw, ushort* __restrict__ xch){
  int idx = blockIdx.x*256 + threadIdx.x;
  int d4  = idx & 255;
  int row = idx >> 8;
  int t = row & (LL-1);
  const ushort* p = xz + (size_t)row*E2V + d4*4;
  ushort4 u1 = *reinterpret_cast<const ushort4*>(p);
  ushort4 u0 = (t>0)    ? *reinterpret_cast<const ushort4*>(p - E2V) : make_ushort4(0,0,0,0);
  ushort4 u2 = (t<LL-1) ? *reinterpret_cast<const ushort4*>(p + E2V) : make_ushort4(0,0,0,0);
  int d = d4*4;
  float w[12];
  #pragma unroll
  for (int i=0;i<12;i++) w[i] = cw[d*3 + i];
  float4 o;
  o.x = bf2f(u0.x)*w[0] + bf2f(u1.x)*w[1]  + bf2f(u2.x)*w[2];
  o.y = bf2f(u0.y)*w[3] + bf2f(u1.y)*w[4]  + bf2f(u2.y)*w[5];
  o.z = bf2f(u0.z)*w[6] + bf2f(u1.z)*w[7]  + bf2f(u2.z)*w[8];
  o.w = bf2f(u0.w)*w[9] + bf2f(u1.w)*w[10] + bf2f(u2.w)*w[11];
  o.x = o.x / (1.f + __expf(-o.x));
  o.y = o.y / (1.f + __expf(-o.y));
  o.z = o.z / (1.f + __expf(-o.z));
  o.w = o.w / (1.f + __expf(-o.w));
  ushort4 H;
  H.x=f2bf(o.x); H.y=f2bf(o.y); H.z=f2bf(o.z); H.w=f2bf(o.w);
  *reinterpret_cast<ushort4*>(xch + (size_t)row*DIMV + d4*4) = H;
}

// ======== scan, one thread per channel d; S=16 state in registers ========
// F/P/E stored as bf16 (verified: absmax unchanged, R12).
__global__ __launch_bounds__(256) void scan_p1(const ushort* __restrict__ dt,
        const float* __restrict__ bc, const float* __restrict__ A_log,
        ushort* __restrict__ F, ushort* __restrict__ P){
  __shared__ float sB[CLEN*32];
  int bid = blockIdx.x;                 // b*(NCHUNK*4) + c*4 + dblk
  int dblk = bid & 3;
  int c  = (bid >> 2) & (NCHUNK-1);
  int b  = bid >> 8;
  int tid = threadIdx.x;
  int d = dblk*256 + tid;
  int row0 = b*LL + c*CLEN;
  ((float4*)sB)[tid] = *((const float4*)(bc + (size_t)row0*32) + tid);
  float a[16];
  {
    const float4* ap = (const float4*)(A_log + d*16);
    #pragma unroll
    for (int q=0;q<4;q++){
      float4 v = ap[q];
      a[q*4+0]=-__expf(v.x); a[q*4+1]=-__expf(v.y);
      a[q*4+2]=-__expf(v.z); a[q*4+3]=-__expf(v.w);
    }
  }
  __syncthreads();
  float st[16];
  #pragma unroll
  for (int s=0;s<16;s++) st[s]=0.f;
  float sdt = 0.f;
  const ushort* dtp = dt + (size_t)row0*DIMV + d;
  for (int t=0;t<CLEN;t++){
    float dtv = bf2f(dtp[(size_t)t*DIMV]);
    sdt += dtv;
    float4 B0 = *(const float4*)&sB[t*32+0];
    float4 B1 = *(const float4*)&sB[t*32+4];
    float4 B2 = *(const float4*)&sB[t*32+8];
    float4 B3 = *(const float4*)&sB[t*32+12];
    float Bv[16] = {B0.x,B0.y,B0.z,B0.w,B1.x,B1.y,B1.z,B1.w,
                    B2.x,B2.y,B2.z,B2.w,B3.x,B3.y,B3.z,B3.w};
    #pragma unroll
    for (int s=0;s<16;s++){
      float dA = __expf(dtv*a[s]);
      st[s] = fmaf(st[s], dA, dtv*Bv[s]);
    }
  }
  size_t o = ((size_t)((b*NCHUNK + c)*DIMV + d))*16;
  #pragma unroll
  for (int q=0;q<4;q++){
    ushort4 fv, pv;
    fv.x=f2bf(st[q*4]);   fv.y=f2bf(st[q*4+1]);
    fv.z=f2bf(st[q*4+2]); fv.w=f2bf(st[q*4+3]);
    pv.x=f2bf(__expf(sdt*a[q*4]));   pv.y=f2bf(__expf(sdt*a[q*4+1]));
    pv.z=f2bf(__expf(sdt*a[q*4+2])); pv.w=f2bf(__expf(sdt*a[q*4+3]));
    *(ushort4*)(F + o + q*4) = fv;
    *(ushort4*)(P + o + q*4) = pv;
  }
}

__global__ __launch_bounds__(256) void scan_p2(const ushort* __restrict__ F,
        const ushort* __restrict__ P, ushort* __restrict__ E){
  int idx = blockIdx.x*256 + threadIdx.x;   // BB*DIMV*SSV = 32768
  int b  = idx >> 14;
  int ds = idx & 16383;
  float e = 0.f;
  for (int c=0;c<NCHUNK;c++){
    size_t o = ((size_t)(b*NCHUNK + c) << 14) + ds;
    E[o] = f2bf(e);
    e = fmaf(bf2f(P[o]), e, bf2f(F[o]));
  }
}

__global__ __launch_bounds__(256) void scan_p3(const ushort* __restrict__ dt,
        const float* __restrict__ bc, const float* __restrict__ A_log,
        const ushort* __restrict__ E, const ushort* __restrict__ xch,
        const ushort* __restrict__ xz, const float* __restrict__ Dp,
        ushort* __restrict__ yh){
  __shared__ float sBC[CLEN*32];
  int bid = blockIdx.x;
  int dblk = bid & 3;
  int c  = (bid >> 2) & (NCHUNK-1);
  int b  = bid >> 8;
  int tid = threadIdx.x;
  int d = dblk*256 + tid;
  int row0 = b*LL + c*CLEN;
  ((float4*)sBC)[tid] = *((const float4*)(bc + (size_t)row0*32) + tid);
  float a[16];
  {
    const float4* ap = (const float4*)(A_log + d*16);
    #pragma unroll
    for (int q=0;q<4;q++){
      float4 v = ap[q];
      a[q*4+0]=-__expf(v.x); a[q*4+1]=-__expf(v.y);
      a[q*4+2]=-__expf(v.z); a[q*4+3]=-__expf(v.w);
    }
  }
  float st[16];
  {
    size_t o = ((size_t)((b*NCHUNK + c)*DIMV + d))*16;
    #pragma unroll
    for (int q=0;q<4;q++){
      ushort4 v = *(const ushort4*)(E + o + q*4);
      st[q*4]=bf2f(v.x); st[q*4+1]=bf2f(v.y); st[q*4+2]=bf2f(v.z); st[q*4+3]=bf2f(v.w);
    }
  }
  float Dv = Dp[d];
  __syncthreads();
  const ushort* dtp = dt + (size_t)row0*DIMV + d;
  for (int t=0;t<CLEN;t++){
    float dtv = bf2f(dtp[(size_t)t*DIMV]);
    float4 B0 = *(const float4*)&sBC[t*32+0];
    float4 B1 = *(const float4*)&sBC[t*32+4];
    float4 B2 = *(const float4*)&sBC[t*32+8];
    float4 B3 = *(const float4*)&sBC[t*32+12];
    float4 C0 = *(const float4*)&sBC[t*32+16];
    float4 C1 = *(const float4*)&sBC[t*32+20];
    float4 C2 = *(const float4*)&sBC[t*32+24];
    float4 C3 = *(const float4*)&sBC[t*32+28];
    float Bv[16] = {B0.x,B0.y,B0.z,B0.w,B1.x,B1.y,B1.z,B1.w,
                    B2.x,B2.y,B2.z,B2.w,B3.x,B3.y,B3.z,B3.w};
    float Cv[16] = {C0.x,C0.y,C0.z,C0.w,C1.x,C1.y,C1.z,C1.w,
                    C2.x,C2.y,C2.z,C2.w,C3.x,C3.y,C3.z,C3.w};
    float y = 0.f;
    #pragma unroll
    for (int s=0;s<16;s++){
      float dA = __expf(dtv*a[s]);
      st[s] = fmaf(st[s], dA, dtv*Bv[s]);
      y = fmaf(st[s], Cv[s], y);
    }
    int row = row0 + t;
    size_t ofs = (size_t)row*DIMV + d;
    float xcv = bf2f(xch[ofs]);
    float zv  = bf2f(xz[(size_t)row*E2V + INNERV + d]);
    float sz  = zv / (1.f + __expf(-zv));
    yh[ofs] = f2bf((y + Dv*xcv)*sz);
  }
}

extern "C" void kernel_launch(void* const* d_in, const int* in_sizes, int n_in,
                              void* d_out, int out_size, void* d_ws, size_t ws_size,
                              hipStream_t stream){
  const float* x     = (const float*)d_in[0];
  const float* gamma = (const float*)d_in[1];
  const float* beta  = (const float*)d_in[2];
  const float* W_in  = (const float*)d_in[3];
  const float* cw    = (const float*)d_in[4];
  const float* W_x   = (const float*)d_in[5];
  const float* W_dt  = (const float*)d_in[6];
  const float* b_dt  = (const float*)d_in[7];
  const float* A_log = (const float*)d_in[8];
  const float* Dp    = (const float*)d_in[9];
  const float* W_out = (const float*)d_in[10];
  float* out = (float*)d_out;
  float* ws  = (float*)d_ws;
  const size_t MB = (size_t)1 << 20;   // 1M floats
  // layout (float units); bf16 buffer of N elems occupies N/2 float slots.
  ushort* xzh = (ushort*)ws;                      // 8M bf16 -> [0,4M)
  ushort* hh  = (ushort*)(ws + 4*MB);             // [4M,6M)  dead after gemm0
  ushort* yh  = (ushort*)(ws + 4*MB);             // p3 writes (hh dead)
  ushort* xch = (ushort*)(ws + 6*MB);             // [6M,8M)
  ushort* dtb = (ushort*)(ws + 8*MB);             // [8M,10M)
  ushort* F   = (ushort*)(ws + 10*MB);            // [10M,11M)
  ushort* P   = (ushort*)(ws + 11*MB);            // [11M,12M)
  ushort* E   = (ushort*)(ws + 12*MB);            // [12M,13M)
  ushort* Wih = (ushort*)(ws + 13*MB);            // [13M,14M)  2M ushorts
  ushort* Wch = (ushort*)(ws + 14*MB);            // [14M,14.6M) 1152x1024 ushorts
  ushort* Woh = (ushort*)(ws + 14*MB + 640*1024); // [14.625M,15.125M)
  float*  bcb = ws + 15*MB + 256*1024;            // [15.25M, +128K floats)

  ln_init<<<4224 + MMV, 256, 0, stream>>>(x, gamma, beta, hh,
                                          W_in, W_dt, W_out, W_x,
                                          Wih, Wch, Woh);
  gemm_bf16<0,128><<<dim3(E2V/128, MMV/128), 256, 0, stream>>>(hh, Wih, xzh, E2V, nullptr);
  conv_silu_kernel<<<(MMV*(DIMV/4))/256, 256, 0, stream>>>(xzh, cw, xch);
  gemm_dtbc<<<dim3(17, MMV/128), 256, 0, stream>>>(xch, Wch, dtb, b_dt, bcb);
  scan_p1<<<BB*NCHUNK*(DIMV/256), 256, 0, stream>>>(dtb, bcb, A_log, F, P);
  scan_p2<<<(BB*DIMV*SSV)/256, 256, 0, stream>>>(F, P, E);
  scan_p3<<<BB*NCHUNK*(DIMV/256), 256, 0, stream>>>(dtb, bcb, A_log, E, xch, xzh, Dp, yh);
  gemm_bf16<2,64><<<dim3(DIMV/64, MMV/128), 256, 0, stream>>>(yh, Woh, out, DIMV, x);
}